// Round 2
// baseline (1026.304 us; speedup 1.0000x reference)
//
#include <hip/hip_runtime.h>
#include <hip/hip_bf16.h>

#define TSTEPS 300
#define INDIM  38
#define H1D    32
#define H2D    20
#define NB     16
#define BTOT   2048

__device__ __forceinline__ float frcp(float x) { return __builtin_amdgcn_rcpf(x); }

__device__ __forceinline__ float fsig(float x) {
    // 1/(1+exp(-x)) ; exp(-x) = exp2(-x*log2(e))
    float e = exp2f(-1.44269504f * x);
    return frcp(1.0f + e);
}
__device__ __forceinline__ float ftanh(float x) {
    // 1 - 2/(1+exp(2x)) : safe at +/-inf
    float e = exp2f(2.88539008f * x);
    return 1.0f - 2.0f * frcp(1.0f + e);
}

__global__ __launch_bounds__(256, 1) void rnn_kernel(
    const float* __restrict__ x,
    const float* __restrict__ Wf1, const float* __restrict__ bf1,
    const float* __restrict__ Wf2, const float* __restrict__ bf2,
    const float* __restrict__ Wb1, const float* __restrict__ bb1,
    const float* __restrict__ Wb2, const float* __restrict__ bb2,
    float* __restrict__ featws)
{
    __shared__ float W1[70 * 128];     // [k][col] row-major
    __shared__ float W2t[80 * 52];     // transposed: [col][k]
    __shared__ float bias1[128];
    __shared__ float bias2[80];
    __shared__ float in1[NB][72];      // [x(38) | h1(32)] padded to 72
    __shared__ float in2[NB][56];      // [h1(32) | h2(20)] padded to 56
    __shared__ float z1[NB][132];      // gates layer1 (132 = 128+4 pad)
    __shared__ float z2[NB][80];       // gates layer2

    const int tid = threadIdx.x;
    const int dir = blockIdx.y;
    const int b0  = blockIdx.x * NB;

    const float* Wa = dir ? Wb1 : Wf1;
    const float* ba = dir ? bb1 : bf1;
    const float* Wb = dir ? Wb2 : Wf2;
    const float* bb = dir ? bb2 : bf2;

    // ---- stage weights into LDS ----
    for (int i = tid; i < 70 * 128; i += 256) W1[i] = Wa[i];
    for (int i = tid; i < 52 * 80; i += 256) {
        int k = i / 80, c = i % 80;
        W2t[c * 52 + k] = Wb[i];
    }
    if (tid < 128) bias1[tid] = ba[tid];
    if (tid < 80)  bias2[tid] = bb[tid];
    // zero ONLY the recurrent-state columns (disjoint from x staging below —
    // overlapping writes from different waves raced in the previous version)
    for (int i = tid; i < NB * 34; i += 256) { int b = i / 34, k = i % 34; in1[b][INDIM + k] = 0.0f; }
    for (int i = tid; i < NB * 24; i += 256) { int b = i / 24, k = i % 24; in2[b][H1D + k] = 0.0f; }
    // stage x for step 0 (writes columns 0..37 only)
    {
        int t0 = dir ? (TSTEPS - 1) : 0;
        for (int i = tid; i < NB * INDIM; i += 256) {
            int b = i / INDIM, k = i % INDIM;
            in1[b][k] = x[((size_t)(b0 + b) * TSTEPS + t0) * INDIM + k];
        }
    }
    __syncthreads();

    // ---- role indices ----
    const int wv   = tid >> 6;           // wave 0..3
    const int lane = tid & 63;
    const int g1_cg = lane & 7;          // col group within wave
    const int g1_bs = lane >> 3;         // batch slot 0..7
    const int g1_c0 = wv * 32 + g1_cg * 4;

    const int cm = tid & 31;             // cell index
    const int cb = tid >> 5;             // batch slot 0..7 (handles cb and cb+8)

    const int g2_c = tid & 15;           // layer2 col base (cols g2_c + 16*g)
    const int g2_b = tid >> 4;           // layer2 batch 0..15

    // x prefetch lanes (i = tid, tid+256, tid+512 over NB*INDIM=608)
    const int xi0_b = tid / INDIM,          xi0_k = tid % INDIM;
    const int xi1_b = (tid + 256) / INDIM,  xi1_k = (tid + 256) % INDIM;
    const int xi2_b = (tid + 512) / INDIM,  xi2_k = (tid + 512) % INDIM; // valid iff tid<96
    const bool has2 = (tid + 512) < NB * INDIM;
    const int tstart = dir ? (TSTEPS - 2) : 1;
    const int dstep  = dir ? -INDIM : INDIM;
    const float* xp0 = x + ((size_t)(b0 + xi0_b) * TSTEPS + tstart) * INDIM + xi0_k;
    const float* xp1 = x + ((size_t)(b0 + xi1_b) * TSTEPS + tstart) * INDIM + xi1_k;
    const float* xp2 = x + ((size_t)(b0 + (has2 ? xi2_b : 0)) * TSTEPS + tstart) * INDIM + (has2 ? xi2_k : 0);

    float c1a = 0.0f, c1b = 0.0f, c2a = 0.0f, c2b = 0.0f;

    for (int s = 0; s < TSTEPS; ++s) {
        // prefetch x(s+1) into registers (consumed after bar1)
        float xr0 = 0.0f, xr1 = 0.0f, xr2 = 0.0f;
        if (s < TSTEPS - 1) {
            xr0 = *xp0; xp0 += dstep;
            xr1 = *xp1; xp1 += dstep;
            if (has2) { xr2 = *xp2; xp2 += dstep; }
        }

        // ---- GEMM1: z1[16][128] = in1[16][70] @ W1[70][128] ----
        float a0x = 0, a0y = 0, a0z = 0, a0w = 0;
        float a1x = 0, a1y = 0, a1z = 0, a1w = 0;
        {
            const float* wp = &W1[g1_c0];
            const float* ia = &in1[g1_bs][0];
            const float* ib = &in1[g1_bs + 8][0];
            #pragma unroll
            for (int k = 0; k < 70; ++k) {
                float4 w = *(const float4*)(wp + k * 128);
                float va = ia[k];
                float vb = ib[k];
                a0x += va * w.x; a0y += va * w.y; a0z += va * w.z; a0w += va * w.w;
                a1x += vb * w.x; a1y += vb * w.y; a1z += vb * w.z; a1w += vb * w.w;
            }
            float4 bz = *(const float4*)&bias1[g1_c0];
            float4 r0 = { a0x + bz.x, a0y + bz.y, a0z + bz.z, a0w + bz.w };
            float4 r1 = { a1x + bz.x, a1y + bz.y, a1z + bz.z, a1w + bz.w };
            *(float4*)&z1[g1_bs][g1_c0]     = r0;
            *(float4*)&z1[g1_bs + 8][g1_c0] = r1;
        }
        __syncthreads(); // bar1

        // ---- Cell1 (batches cb, cb+8) + x(s+1) LDS store ----
        {
            float zi = z1[cb][cm], zj = z1[cb][cm + 32], zf = z1[cb][cm + 64], zo = z1[cb][cm + 96];
            c1a = c1a * fsig(zf + 1.0f) + fsig(zi) * ftanh(zj);
            float h = ftanh(c1a) * fsig(zo);
            in1[cb][INDIM + cm] = h;
            in2[cb][cm] = h;

            zi = z1[cb + 8][cm]; zj = z1[cb + 8][cm + 32]; zf = z1[cb + 8][cm + 64]; zo = z1[cb + 8][cm + 96];
            c1b = c1b * fsig(zf + 1.0f) + fsig(zi) * ftanh(zj);
            float h2v = ftanh(c1b) * fsig(zo);
            in1[cb + 8][INDIM + cm] = h2v;
            in2[cb + 8][cm] = h2v;
        }
        if (s < TSTEPS - 1) {
            in1[xi0_b][xi0_k] = xr0;
            in1[xi1_b][xi1_k] = xr1;
            if (has2) in1[xi2_b][xi2_k] = xr2;
        }
        __syncthreads(); // bar2

        // ---- GEMM2: z2[16][80] = in2[16][52] @ W2[52][80] (W2t is [col][k]) ----
        {
            float s0 = 0, s1 = 0, s2 = 0, s3 = 0, s4 = 0;
            const float* ip = &in2[g2_b][0];
            const float* w0 = &W2t[(g2_c)      * 52];
            const float* w1 = &W2t[(g2_c + 16) * 52];
            const float* w2 = &W2t[(g2_c + 32) * 52];
            const float* w3 = &W2t[(g2_c + 48) * 52];
            const float* w4 = &W2t[(g2_c + 64) * 52];
            #pragma unroll
            for (int k = 0; k < 52; ++k) {
                float av = ip[k];
                s0 += av * w0[k];
                s1 += av * w1[k];
                s2 += av * w2[k];
                s3 += av * w3[k];
                s4 += av * w4[k];
            }
            z2[g2_b][g2_c]      = s0 + bias2[g2_c];
            z2[g2_b][g2_c + 16] = s1 + bias2[g2_c + 16];
            z2[g2_b][g2_c + 32] = s2 + bias2[g2_c + 32];
            z2[g2_b][g2_c + 48] = s3 + bias2[g2_c + 48];
            z2[g2_b][g2_c + 64] = s4 + bias2[g2_c + 64];
        }
        __syncthreads(); // bar3

        // ---- Cell2 (batches cb, cb+8; cells cm<20) ----
        if (cm < H2D) {
            float zi = z2[cb][cm], zj = z2[cb][cm + 20], zf = z2[cb][cm + 40], zo = z2[cb][cm + 60];
            c2a = c2a * fsig(zf + 1.0f) + fsig(zi) * ftanh(zj);
            float ha = ftanh(c2a) * fsig(zo);
            in2[cb][H1D + cm] = ha;

            zi = z2[cb + 8][cm]; zj = z2[cb + 8][cm + 20]; zf = z2[cb + 8][cm + 40]; zo = z2[cb + 8][cm + 60];
            c2b = c2b * fsig(zf + 1.0f) + fsig(zi) * ftanh(zj);
            float hb = ftanh(c2b) * fsig(zo);
            in2[cb + 8][H1D + cm] = hb;

            if (s == 0 || s == TSTEPS - 1) {
                // feat layout per batch: [fw(t=0) | bw(t=0) | fw(t=T-1) | bw(t=T-1)]
                // dir0: s=0 -> off 0,  s=299 -> off 40
                // dir1: s=0 -> off 60, s=299 -> off 20
                int off = (s == 0) ? (dir ? 60 : 0) : (dir ? 20 : 40);
                featws[(size_t)(b0 + cb) * 80 + off + cm]     = ha;
                featws[(size_t)(b0 + cb + 8) * 80 + off + cm] = hb;
            }
        }
        // no barrier needed here: Cell2 touches only z2 (next write: post-bar2 of s+1)
        // and in2[32..51] (next read: post-bar2 of s+1)
    }
}

__global__ __launch_bounds__(64) void fc_kernel(
    const float* __restrict__ featws,
    const float* __restrict__ Wfc1, const float* __restrict__ bfc1,
    const float* __restrict__ Wfc2, const float* __restrict__ bfc2,
    const float* __restrict__ Wfc3, const float* __restrict__ bfc3,
    float* __restrict__ out)
{
    __shared__ float f[80];
    __shared__ float h1b[80];
    __shared__ float h2b[20];
    const int b = blockIdx.x;
    const int lane = threadIdx.x;

    for (int i = lane; i < 80; i += 64) f[i] = featws[(size_t)b * 80 + i];
    __syncthreads();

    for (int j = lane; j < 80; j += 64) {
        float s = bfc1[j];
        #pragma unroll 8
        for (int k = 0; k < 80; ++k) s += f[k] * Wfc1[k * 80 + j];
        h1b[j] = ftanh(s);
    }
    __syncthreads();

    if (lane < 20) {
        float s = bfc2[lane];
        #pragma unroll 8
        for (int k = 0; k < 80; ++k) s += h1b[k] * Wfc2[k * 20 + lane];
        h2b[lane] = ftanh(s);
    }
    __syncthreads();

    if (lane < 3) {
        float s = bfc3[lane];
        #pragma unroll
        for (int k = 0; k < 20; ++k) s += h2b[k] * Wfc3[k * 3 + lane];
        out[(size_t)b * 3 + lane] = s;
    }
}

extern "C" void kernel_launch(void* const* d_in, const int* in_sizes, int n_in,
                              void* d_out, int out_size, void* d_ws, size_t ws_size,
                              hipStream_t stream) {
    const float* x    = (const float*)d_in[0];
    const float* Wf1  = (const float*)d_in[1];
    const float* bf1  = (const float*)d_in[2];
    const float* Wf2  = (const float*)d_in[3];
    const float* bf2  = (const float*)d_in[4];
    const float* Wb1  = (const float*)d_in[5];
    const float* bb1  = (const float*)d_in[6];
    const float* Wb2  = (const float*)d_in[7];
    const float* bb2  = (const float*)d_in[8];
    const float* Wfc1 = (const float*)d_in[9];
    const float* bfc1 = (const float*)d_in[10];
    const float* Wfc2 = (const float*)d_in[11];
    const float* bfc2 = (const float*)d_in[12];
    const float* Wfc3 = (const float*)d_in[13];
    const float* bfc3 = (const float*)d_in[14];

    float* feat = (float*)d_ws; // 2048*80*4 = 655360 B

    rnn_kernel<<<dim3(BTOT / NB, 2), 256, 0, stream>>>(
        x, Wf1, bf1, Wf2, bf2, Wb1, bb1, Wb2, bb2, feat);
    fc_kernel<<<BTOT, 64, 0, stream>>>(
        feat, Wfc1, bfc1, Wfc2, bfc2, Wfc3, bfc3, (float*)d_out);
}

// Round 3
// 544.278 us; speedup vs baseline: 1.8856x; 1.8856x over previous
//
#include <hip/hip_runtime.h>
#include <hip/hip_bf16.h>

#define TSTEPS 300
#define INDIM  38

typedef __attribute__((ext_vector_type(4))) float    float4_;
typedef __attribute__((ext_vector_type(8))) short    short8;
typedef __attribute__((ext_vector_type(4))) unsigned u32x4;

__device__ __forceinline__ float frcp(float x){ return __builtin_amdgcn_rcpf(x); }
__device__ __forceinline__ float fsig(float x){ return frcp(1.0f + exp2f(-1.44269504f*x)); }
__device__ __forceinline__ float ftanh(float x){ return 1.0f - 2.0f*frcp(1.0f + exp2f(2.88539008f*x)); }

// round-to-nearest-even fp32 -> bf16 (as u16)
__device__ __forceinline__ unsigned bf16rne(float f){
    unsigned u = __float_as_uint(f);
    return (u + 0x7FFFu + ((u>>16)&1u)) >> 16;
}
// pack value as (hi bf16) | (lo bf16 << 16), hi+lo ~= f to ~2^-17 rel
__device__ __forceinline__ unsigned packhl(float f){
    unsigned hi = bf16rne(f);
    float lo = f - __uint_as_float(hi<<16);
    return hi | (bf16rne(lo)<<16);
}
__device__ __forceinline__ short8 mk8(unsigned a,unsigned b,unsigned c,unsigned d){
    union { unsigned u[4]; short8 s; } t; t.u[0]=a; t.u[1]=b; t.u[2]=c; t.u[3]=d; return t.s;
}
// w = packed k {0..3}, v = packed k {16..19} (relative 4g+j / 16+4g+j); build hi-frag & lo-frag
__device__ __forceinline__ void mkfrag(u32x4 w, u32x4 v, short8& fh, short8& fl){
    fh = mk8(__builtin_amdgcn_perm(w.y,w.x,0x05040100u), __builtin_amdgcn_perm(w.w,w.z,0x05040100u),
             __builtin_amdgcn_perm(v.y,v.x,0x05040100u), __builtin_amdgcn_perm(v.w,v.z,0x05040100u));
    fl = mk8(__builtin_amdgcn_perm(w.y,w.x,0x07060302u), __builtin_amdgcn_perm(w.w,w.z,0x07060302u),
             __builtin_amdgcn_perm(v.y,v.x,0x07060302u), __builtin_amdgcn_perm(v.w,v.z,0x07060302u));
}
__device__ __forceinline__ float4_ bmfma(short8 a, short8 b, float4_ c){
    return __builtin_amdgcn_mfma_f32_16x16x32_bf16(a, b, c, 0, 0, 0);
}

// LDS layouts (all packed hi|lo u32 unless noted):
//  W1P[8ct][16col][72k]  k: 0..31 = h1 (W1 rows 38..69), 32..69 = x (rows 0..37), 70..71 zero
//  W2P[5ct][16col][64k]  k: 0..31 = h1, 32..51 = h2, 52..63 zero
//  h1P[2][16b][36k]      k=cell 0..31  (double buffered by step parity)
//  h2P[2][16b][36k]      k=cell 0..19, 20..31 zero
//  xP [2][16b][40k]      k=x-dim 0..37, 38..39 zero
//  z2s[16b][84]          fp32 layer-2 gate pre-activations

__global__ __launch_bounds__(256,1) void rnn_kernel(
    const float* __restrict__ x,
    const float* __restrict__ Wf1, const float* __restrict__ bf1,
    const float* __restrict__ Wf2, const float* __restrict__ bf2,
    const float* __restrict__ Wb1, const float* __restrict__ bb1,
    const float* __restrict__ Wb2, const float* __restrict__ bb2,
    float* __restrict__ featws)
{
    __shared__ __attribute__((aligned(16))) unsigned W1P[8][16][72];
    __shared__ __attribute__((aligned(16))) unsigned W2P[5][16][64];
    __shared__ __attribute__((aligned(16))) unsigned h1P[2][16][36];
    __shared__ __attribute__((aligned(16))) unsigned h2P[2][16][36];
    __shared__ __attribute__((aligned(16))) unsigned xP [2][16][40];
    __shared__ float z2s[16][84];

    const int tid = threadIdx.x;
    const int dir = blockIdx.y;
    const int b0  = blockIdx.x * 16;

    const float* W1s = dir ? Wb1 : Wf1;
    const float* b1s = dir ? bb1 : bf1;
    const float* W2s = dir ? Wb2 : Wf2;
    const float* b2s = dir ? bb2 : bf2;

    // ---------------- pre-loop staging ----------------
    for (int idx = tid; idx < 8*16*72; idx += 256) ((unsigned*)W1P)[idx] = 0u;
    for (int idx = tid; idx < 5*16*64; idx += 256) ((unsigned*)W2P)[idx] = 0u;
    for (int idx = tid; idx < 2*16*36; idx += 256) ((unsigned*)h1P)[idx] = 0u;
    for (int idx = tid; idx < 2*16*36; idx += 256) ((unsigned*)h2P)[idx] = 0u;
    for (int idx = tid; idx < 2*16*40; idx += 256) ((unsigned*)xP )[idx] = 0u;
    __syncthreads();
    for (int idx = tid; idx < 70*128; idx += 256){
        int k = idx >> 7, c = idx & 127;
        int kd = (k < INDIM) ? (32 + k) : (k - INDIM);   // [h1 | x] ordering
        W1P[c>>4][c&15][kd] = packhl(W1s[idx]);
    }
    for (int idx = tid; idx < 52*80; idx += 256){
        int k = idx / 80, c = idx % 80;
        W2P[c/16][c&15][k] = packhl(W2s[idx]);
    }
    {   // x(step 0)
        int tt = dir ? (TSTEPS-1) : 0;
        for (int v = tid; v < 16*INDIM; v += 256){
            int b = v / INDIM, xk = v % INDIM;
            xP[0][b][xk] = packhl(x[((size_t)(b0+b)*TSTEPS + tt)*INDIM + xk]);
        }
    }
    __syncthreads();

    const int wv = tid >> 6;
    const int ln = tid & 63;
    const int g  = ln >> 4;
    const int cl = ln & 15;

    if (wv < 2) {
        // ================= waves 0,1 : layer 1 (step s = i) =================
        // tiles {wv, wv+2, wv+4, wv+6} -> lane holds i,j,f,o of cell c=16*wv+cl, batches 4g+r
        short8 B1h[4][3], B1l[4][3];
        #pragma unroll
        for (int q = 0; q < 4; ++q){
            int T = wv + 2*q;
            #pragma unroll
            for (int kt = 0; kt < 3; ++kt){
                u32x4 w, v;
                if (kt < 2 || g < 2) w = *(const u32x4*)&W1P[T][cl][kt*32 + 4*g];
                else                 w = u32x4{0,0,0,0};
                if (kt < 2)          v = *(const u32x4*)&W1P[T][cl][kt*32 + 16 + 4*g];
                else                 v = u32x4{0,0,0,0};   // k 80..95 all pad
                mkfrag(w, v, B1h[q][kt], B1l[q][kt]);
            }
        }
        const int c = 16*wv + cl;
        const float bi = b1s[c], bj = b1s[c+32], bfv = b1s[c+64] + 1.0f, bo = b1s[c+96];
        float c1[4] = {0.f,0.f,0.f,0.f};

        for (int i = 0; i <= TSTEPS; ++i){
            float4_ acc[4] = {{0,0,0,0},{0,0,0,0},{0,0,0,0},{0,0,0,0}};
            if (i < TSTEPS){
                const int pr = (i+1)&1;   // h1(s-1)
                const int px = i&1;       // x(s)
                short8 Ah[3], Al[3];
                {
                    u32x4 a0 = *(const u32x4*)&h1P[pr][cl][4*g];
                    u32x4 a1 = *(const u32x4*)&h1P[pr][cl][16 + 4*g];
                    mkfrag(a0, a1, Ah[0], Al[0]);
                    u32x4 x0 = *(const u32x4*)&xP[px][cl][4*g];
                    u32x4 x1 = *(const u32x4*)&xP[px][cl][16 + 4*g];
                    mkfrag(x0, x1, Ah[1], Al[1]);
                    u32x4 x2; 
                    if (g < 2) x2 = *(const u32x4*)&xP[px][cl][32 + 4*g];
                    else       x2 = u32x4{0,0,0,0};
                    u32x4 x3 = u32x4{0,0,0,0};
                    mkfrag(x2, x3, Ah[2], Al[2]);
                }
                #pragma unroll
                for (int kt = 0; kt < 3; ++kt){
                    #pragma unroll
                    for (int q = 0; q < 4; ++q) acc[q] = bmfma(Ah[kt], B1h[q][kt], acc[q]);
                    #pragma unroll
                    for (int q = 0; q < 4; ++q) acc[q] = bmfma(Ah[kt], B1l[q][kt], acc[q]);
                    #pragma unroll
                    for (int q = 0; q < 4; ++q) acc[q] = bmfma(Al[kt], B1h[q][kt], acc[q]);
                }
            }
            __syncthreads();   // barY
            if (i < TSTEPS){
                const int pw = i&1;
                #pragma unroll
                for (int r = 0; r < 4; ++r){
                    float zi = acc[0][r] + bi;
                    float zj = acc[1][r] + bj;
                    float zf = acc[2][r] + bfv;
                    float zo = acc[3][r] + bo;
                    c1[r] = c1[r]*fsig(zf) + fsig(zi)*ftanh(zj);
                    float h = ftanh(c1[r])*fsig(zo);
                    h1P[pw][4*g + r][c] = packhl(h);
                }
            }
            __syncthreads();   // barX
        }
    } else {
        // ================= waves 2,3 : layer 2 (step s2 = i-1) + x staging =================
        const int nT = (wv == 2) ? 3 : 2;
        const int Tb = (wv == 2) ? 0 : 3;
        short8 B2h[3][2], B2l[3][2];
        #pragma unroll
        for (int q = 0; q < 3; ++q) if (q < nT){
            int T = Tb + q;
            #pragma unroll
            for (int kt = 0; kt < 2; ++kt){
                u32x4 w = *(const u32x4*)&W2P[T][cl][kt*32 + 4*g];
                u32x4 v = *(const u32x4*)&W2P[T][cl][kt*32 + 16 + 4*g];
                mkfrag(w, v, B2h[q][kt], B2l[q][kt]);
            }
        }
        const int u = tid & 127;
        // cell slots: e = u + 128*m, e = c*16 + b
        int ec[3], eb[3]; bool ev[3];
        float bi2[3], bj2[3], bf2v[3], bo2[3], c2[3];
        #pragma unroll
        for (int m = 0; m < 3; ++m){
            int e = u + 128*m; ev[m] = (e < 320);
            int es = ev[m] ? e : 0;
            ec[m] = es >> 4; eb[m] = es & 15; c2[m] = 0.f;
            if (ev[m]){ bi2[m] = b2s[ec[m]]; bj2[m] = b2s[ec[m]+20]; bf2v[m] = b2s[ec[m]+40] + 1.0f; bo2[m] = b2s[ec[m]+60]; }
            else      { bi2[m]=bj2[m]=bf2v[m]=bo2[m]=0.f; }
        }
        // x prefetch slots: v = u + 128*m over 16*38=608
        int vbi[5], vxi[5]; bool vv[5]; float xr[5];
        #pragma unroll
        for (int m = 0; m < 5; ++m){
            int v = u + 128*m; vv[m] = (v < 16*INDIM);
            int vs = vv[m] ? v : 0;
            vbi[m] = vs / INDIM; vxi[m] = vs % INDIM; xr[m] = 0.f;
        }
        {   // preload x(step 1)
            int tt = dir ? (TSTEPS-2) : 1;
            #pragma unroll
            for (int m = 0; m < 5; ++m) if (vv[m])
                xr[m] = x[((size_t)(b0+vbi[m])*TSTEPS + tt)*INDIM + vxi[m]];
        }

        for (int i = 0; i <= TSTEPS; ++i){
            // stage x(s+1) into xP[(i+1)&1]; then prefetch x(s+2)
            if (i <= TSTEPS-2){
                const int pxw = (i+1)&1;
                #pragma unroll
                for (int m = 0; m < 5; ++m) if (vv[m])
                    xP[pxw][vbi[m]][vxi[m]] = packhl(xr[m]);
            }
            if (i <= TSTEPS-3){
                int tt = dir ? (TSTEPS-1-(i+2)) : (i+2);
                #pragma unroll
                for (int m = 0; m < 5; ++m) if (vv[m])
                    xr[m] = x[((size_t)(b0+vbi[m])*TSTEPS + tt)*INDIM + vxi[m]];
            }
            if (i >= 1){
                const int pr = (i+1)&1;   // h1(i-1)
                const int ph = i&1;       // h2(i-2)
                short8 A2h[2], A2l[2];
                {
                    u32x4 a0 = *(const u32x4*)&h1P[pr][cl][4*g];
                    u32x4 a1 = *(const u32x4*)&h1P[pr][cl][16 + 4*g];
                    mkfrag(a0, a1, A2h[0], A2l[0]);
                    u32x4 h0 = *(const u32x4*)&h2P[ph][cl][4*g];
                    u32x4 h1_ = *(const u32x4*)&h2P[ph][cl][16 + 4*g];
                    mkfrag(h0, h1_, A2h[1], A2l[1]);
                }
                float4_ a2[3] = {{0,0,0,0},{0,0,0,0},{0,0,0,0}};
                #pragma unroll
                for (int kt = 0; kt < 2; ++kt){
                    #pragma unroll
                    for (int q = 0; q < 3; ++q) if (q < nT) a2[q] = bmfma(A2h[kt], B2h[q][kt], a2[q]);
                    #pragma unroll
                    for (int q = 0; q < 3; ++q) if (q < nT) a2[q] = bmfma(A2h[kt], B2l[q][kt], a2[q]);
                    #pragma unroll
                    for (int q = 0; q < 3; ++q) if (q < nT) a2[q] = bmfma(A2l[kt], B2h[q][kt], a2[q]);
                }
                #pragma unroll
                for (int q = 0; q < 3; ++q) if (q < nT){
                    #pragma unroll
                    for (int r = 0; r < 4; ++r)
                        z2s[4*g + r][16*(Tb+q) + cl] = a2[q][r];
                }
            }
            __syncthreads();   // barY
            if (i >= 1){
                const int pw = (i+1)&1;   // h2(i-1) buffer
                #pragma unroll
                for (int m = 0; m < 3; ++m) if (ev[m]){
                    int cc = ec[m], bb = eb[m];
                    float zi = z2s[bb][cc]      + bi2[m];
                    float zj = z2s[bb][cc+20]   + bj2[m];
                    float zf = z2s[bb][cc+40]   + bf2v[m];
                    float zo = z2s[bb][cc+60]   + bo2[m];
                    c2[m] = c2[m]*fsig(zf) + fsig(zi)*ftanh(zj);
                    float h = ftanh(c2[m])*fsig(zo);
                    h2P[pw][bb][cc] = packhl(h);
                    if (i == 1 || i == TSTEPS){
                        int off = (i == 1) ? (dir ? 60 : 0) : (dir ? 20 : 40);
                        featws[(size_t)(b0+bb)*80 + off + cc] = h;
                    }
                }
            }
            __syncthreads();   // barX
        }
    }
}

__global__ __launch_bounds__(64) void fc_kernel(
    const float* __restrict__ featws,
    const float* __restrict__ Wfc1, const float* __restrict__ bfc1,
    const float* __restrict__ Wfc2, const float* __restrict__ bfc2,
    const float* __restrict__ Wfc3, const float* __restrict__ bfc3,
    float* __restrict__ out)
{
    __shared__ float f[80];
    __shared__ float h1b[80];
    __shared__ float h2b[20];
    const int b = blockIdx.x;
    const int lane = threadIdx.x;

    for (int i = lane; i < 80; i += 64) f[i] = featws[(size_t)b*80 + i];
    __syncthreads();
    for (int j = lane; j < 80; j += 64){
        float s = bfc1[j];
        #pragma unroll 8
        for (int k = 0; k < 80; ++k) s += f[k]*Wfc1[k*80 + j];
        h1b[j] = ftanh(s);
    }
    __syncthreads();
    if (lane < 20){
        float s = bfc2[lane];
        #pragma unroll 8
        for (int k = 0; k < 80; ++k) s += h1b[k]*Wfc2[k*20 + lane];
        h2b[lane] = ftanh(s);
    }
    __syncthreads();
    if (lane < 3){
        float s = bfc3[lane];
        #pragma unroll
        for (int k = 0; k < 20; ++k) s += h2b[k]*Wfc3[k*3 + lane];
        out[(size_t)b*3 + lane] = s;
    }
}

extern "C" void kernel_launch(void* const* d_in, const int* in_sizes, int n_in,
                              void* d_out, int out_size, void* d_ws, size_t ws_size,
                              hipStream_t stream) {
    const float* x    = (const float*)d_in[0];
    const float* Wf1  = (const float*)d_in[1];
    const float* bf1  = (const float*)d_in[2];
    const float* Wf2  = (const float*)d_in[3];
    const float* bf2  = (const float*)d_in[4];
    const float* Wb1  = (const float*)d_in[5];
    const float* bb1  = (const float*)d_in[6];
    const float* Wb2  = (const float*)d_in[7];
    const float* bb2  = (const float*)d_in[8];
    const float* Wfc1 = (const float*)d_in[9];
    const float* bfc1 = (const float*)d_in[10];
    const float* Wfc2 = (const float*)d_in[11];
    const float* bfc2 = (const float*)d_in[12];
    const float* Wfc3 = (const float*)d_in[13];
    const float* bfc3 = (const float*)d_in[14];

    float* feat = (float*)d_ws; // 2048*80*4 = 655360 B

    rnn_kernel<<<dim3(128, 2), 256, 0, stream>>>(
        x, Wf1, bf1, Wf2, bf2, Wb1, bb1, Wb2, bb2, feat);
    fc_kernel<<<2048, 64, 0, stream>>>(
        feat, Wfc1, bfc1, Wfc2, bfc2, Wfc3, bfc3, (float*)d_out);
}

// Round 4
// 537.966 us; speedup vs baseline: 1.9078x; 1.0117x over previous
//
#include <hip/hip_runtime.h>
#include <hip/hip_bf16.h>

#define TSTEPS 300
#define INDIM  38
#define NB2    8     // batches per block

typedef __attribute__((ext_vector_type(4))) float    float4_;
typedef __attribute__((ext_vector_type(8))) short    short8;
typedef __attribute__((ext_vector_type(4))) unsigned u32x4;

__device__ __forceinline__ float frcp(float x){ return __builtin_amdgcn_rcpf(x); }
__device__ __forceinline__ float fsig(float x){ return frcp(1.0f + exp2f(-1.44269504f*x)); }
__device__ __forceinline__ float ftanh(float x){ return 1.0f - 2.0f*frcp(1.0f + exp2f(2.88539008f*x)); }

// round-to-nearest-even fp32 -> bf16 (as u16)
__device__ __forceinline__ unsigned bf16rne(float f){
    unsigned u = __float_as_uint(f);
    return (u + 0x7FFFu + ((u>>16)&1u)) >> 16;
}
// pack value as (hi bf16) | (lo bf16 << 16), hi+lo ~= f to ~2^-17 rel
__device__ __forceinline__ unsigned packhl(float f){
    unsigned hi = bf16rne(f);
    float lo = f - __uint_as_float(hi<<16);
    return hi | (bf16rne(lo)<<16);
}
__device__ __forceinline__ short8 mk8(unsigned a,unsigned b,unsigned c,unsigned d){
    union { unsigned u[4]; short8 s; } t; t.u[0]=a; t.u[1]=b; t.u[2]=c; t.u[3]=d; return t.s;
}
// w = packed k {0..3}, v = packed k {16..19} (relative 4g+j / 16+4g+j); build hi-frag & lo-frag
__device__ __forceinline__ void mkfrag(u32x4 w, u32x4 v, short8& fh, short8& fl){
    fh = mk8(__builtin_amdgcn_perm(w.y,w.x,0x05040100u), __builtin_amdgcn_perm(w.w,w.z,0x05040100u),
             __builtin_amdgcn_perm(v.y,v.x,0x05040100u), __builtin_amdgcn_perm(v.w,v.z,0x05040100u));
    fl = mk8(__builtin_amdgcn_perm(w.y,w.x,0x07060302u), __builtin_amdgcn_perm(w.w,w.z,0x07060302u),
             __builtin_amdgcn_perm(v.y,v.x,0x07060302u), __builtin_amdgcn_perm(v.w,v.z,0x07060302u));
}
__device__ __forceinline__ float4_ bmfma(short8 a, short8 b, float4_ c){
    return __builtin_amdgcn_mfma_f32_16x16x32_bf16(a, b, c, 0, 0, 0);
}

// LDS layouts (all packed hi|lo u32 unless noted):
//  W1P[8ct][16col][72k]  k: 0..31 = h1 (W1 rows 38..69), 32..69 = x (rows 0..37), 70..71 zero
//  W2P[5ct][16col][64k]  k: 0..31 = h1, 32..51 = h2, 52..63 zero
//  h1P[2][16b][36k]      k=cell 0..31  (double buffered by step parity; b>=NB2 garbage)
//  h2P[2][16b][36k]      k=cell 0..19, 20..31 zero
//  xP [2][16b][40k]      k=x-dim 0..37, 38..39 zero; b>=NB2 stays zero
//  z2s[16b][84]          fp32 layer-2 gate pre-activations

__global__ __launch_bounds__(256,2) void rnn_kernel(
    const float* __restrict__ x,
    const float* __restrict__ Wf1, const float* __restrict__ bf1,
    const float* __restrict__ Wf2, const float* __restrict__ bf2,
    const float* __restrict__ Wb1, const float* __restrict__ bb1,
    const float* __restrict__ Wb2, const float* __restrict__ bb2,
    float* __restrict__ featws)
{
    __shared__ __attribute__((aligned(16))) unsigned W1P[8][16][72];
    __shared__ __attribute__((aligned(16))) unsigned W2P[5][16][64];
    __shared__ __attribute__((aligned(16))) unsigned h1P[2][16][36];
    __shared__ __attribute__((aligned(16))) unsigned h2P[2][16][36];
    __shared__ __attribute__((aligned(16))) unsigned xP [2][16][40];
    __shared__ float z2s[16][84];

    const int tid = threadIdx.x;
    const int dir = blockIdx.y;
    const int b0  = blockIdx.x * NB2;

    const float* W1s = dir ? Wb1 : Wf1;
    const float* b1s = dir ? bb1 : bf1;
    const float* W2s = dir ? Wb2 : Wf2;
    const float* b2s = dir ? bb2 : bf2;

    // ---------------- pre-loop staging ----------------
    for (int idx = tid; idx < 8*16*72; idx += 256) ((unsigned*)W1P)[idx] = 0u;
    for (int idx = tid; idx < 5*16*64; idx += 256) ((unsigned*)W2P)[idx] = 0u;
    for (int idx = tid; idx < 2*16*36; idx += 256) ((unsigned*)h1P)[idx] = 0u;
    for (int idx = tid; idx < 2*16*36; idx += 256) ((unsigned*)h2P)[idx] = 0u;
    for (int idx = tid; idx < 2*16*40; idx += 256) ((unsigned*)xP )[idx] = 0u;
    __syncthreads();
    for (int idx = tid; idx < 70*128; idx += 256){
        int k = idx >> 7, c = idx & 127;
        int kd = (k < INDIM) ? (32 + k) : (k - INDIM);   // [h1 | x] ordering
        W1P[c>>4][c&15][kd] = packhl(W1s[idx]);
    }
    for (int idx = tid; idx < 52*80; idx += 256){
        int k = idx / 80, c = idx % 80;
        W2P[c/16][c&15][k] = packhl(W2s[idx]);
    }
    {   // x(step 0), batches 0..NB2-1 only (rest stays zero)
        int tt = dir ? (TSTEPS-1) : 0;
        for (int v = tid; v < NB2*INDIM; v += 256){
            int b = v / INDIM, xk = v % INDIM;
            xP[0][b][xk] = packhl(x[((size_t)(b0+b)*TSTEPS + tt)*INDIM + xk]);
        }
    }
    __syncthreads();

    const int wv = tid >> 6;
    const int ln = tid & 63;
    const int g  = ln >> 4;
    const int cl = ln & 15;

    if (wv < 2) {
        // ================= waves 0,1 : layer 1 (step s = i) =================
        short8 B1h[4][3], B1l[4][3];
        #pragma unroll
        for (int q = 0; q < 4; ++q){
            int T = wv + 2*q;
            #pragma unroll
            for (int kt = 0; kt < 3; ++kt){
                u32x4 w, v;
                if (kt < 2 || g < 2) w = *(const u32x4*)&W1P[T][cl][kt*32 + 4*g];
                else                 w = u32x4{0,0,0,0};
                if (kt < 2)          v = *(const u32x4*)&W1P[T][cl][kt*32 + 16 + 4*g];
                else                 v = u32x4{0,0,0,0};
                mkfrag(w, v, B1h[q][kt], B1l[q][kt]);
            }
        }
        const int c = 16*wv + cl;
        const float bi = b1s[c], bj = b1s[c+32], bfv = b1s[c+64] + 1.0f, bo = b1s[c+96];
        float c1[4] = {0.f,0.f,0.f,0.f};

        #pragma unroll 2
        for (int i = 0; i <= TSTEPS; ++i){
            float4_ acc[4] = {{0,0,0,0},{0,0,0,0},{0,0,0,0},{0,0,0,0}};
            if (i < TSTEPS){
                const int pr = (i+1)&1;   // h1(s-1)
                const int px = i&1;       // x(s)
                short8 Ah[3], Al[3];
                {
                    u32x4 a0 = *(const u32x4*)&h1P[pr][cl][4*g];
                    u32x4 a1 = *(const u32x4*)&h1P[pr][cl][16 + 4*g];
                    mkfrag(a0, a1, Ah[0], Al[0]);
                    u32x4 x0 = *(const u32x4*)&xP[px][cl][4*g];
                    u32x4 x1 = *(const u32x4*)&xP[px][cl][16 + 4*g];
                    mkfrag(x0, x1, Ah[1], Al[1]);
                    u32x4 x2;
                    if (g < 2) x2 = *(const u32x4*)&xP[px][cl][32 + 4*g];
                    else       x2 = u32x4{0,0,0,0};
                    u32x4 x3 = u32x4{0,0,0,0};
                    mkfrag(x2, x3, Ah[2], Al[2]);
                }
                #pragma unroll
                for (int kt = 0; kt < 3; ++kt){
                    #pragma unroll
                    for (int q = 0; q < 4; ++q) acc[q] = bmfma(Ah[kt], B1h[q][kt], acc[q]);
                    #pragma unroll
                    for (int q = 0; q < 4; ++q) acc[q] = bmfma(Ah[kt], B1l[q][kt], acc[q]);
                    #pragma unroll
                    for (int q = 0; q < 4; ++q) acc[q] = bmfma(Al[kt], B1h[q][kt], acc[q]);
                }
            }
            __syncthreads();   // barY
            if (i < TSTEPS){
                const int pw = i&1;
                #pragma unroll
                for (int r = 0; r < 4; ++r){
                    float zi = acc[0][r] + bi;
                    float zj = acc[1][r] + bj;
                    float zf = acc[2][r] + bfv;
                    float zo = acc[3][r] + bo;
                    c1[r] = c1[r]*fsig(zf) + fsig(zi)*ftanh(zj);
                    float h = ftanh(c1[r])*fsig(zo);
                    h1P[pw][4*g + r][c] = packhl(h);
                }
            }
            __syncthreads();   // barX
        }
    } else {
        // ================= waves 2,3 : layer 2 (step s2 = i-1) + x staging =================
        const int nT = (wv == 2) ? 3 : 2;
        const int Tb = (wv == 2) ? 0 : 3;
        short8 B2h[3][2], B2l[3][2];
        #pragma unroll
        for (int q = 0; q < 3; ++q) if (q < nT){
            int T = Tb + q;
            #pragma unroll
            for (int kt = 0; kt < 2; ++kt){
                u32x4 w = *(const u32x4*)&W2P[T][cl][kt*32 + 4*g];
                u32x4 v = *(const u32x4*)&W2P[T][cl][kt*32 + 16 + 4*g];
                mkfrag(w, v, B2h[q][kt], B2l[q][kt]);
            }
        }
        const int u = tid & 127;
        // cell slots: e = u + 128*m, e = c*16 + b  (b >= NB2 computed but never exported)
        int ec[3], eb[3]; bool ev[3];
        float bi2[3], bj2[3], bf2v[3], bo2[3], c2[3];
        #pragma unroll
        for (int m = 0; m < 3; ++m){
            int e = u + 128*m; ev[m] = (e < 320);
            int es = ev[m] ? e : 0;
            ec[m] = es >> 4; eb[m] = es & 15; c2[m] = 0.f;
            if (ev[m]){ bi2[m] = b2s[ec[m]]; bj2[m] = b2s[ec[m]+20]; bf2v[m] = b2s[ec[m]+40] + 1.0f; bo2[m] = b2s[ec[m]+60]; }
            else      { bi2[m]=bj2[m]=bf2v[m]=bo2[m]=0.f; }
        }
        // x prefetch slots: v = u + 128*m over NB2*38=304
        int vbi[3], vxi[3]; bool vv[3]; float xr[3];
        #pragma unroll
        for (int m = 0; m < 3; ++m){
            int v = u + 128*m; vv[m] = (v < NB2*INDIM);
            int vs = vv[m] ? v : 0;
            vbi[m] = vs / INDIM; vxi[m] = vs % INDIM; xr[m] = 0.f;
        }
        {   // preload x(step 1)
            int tt = dir ? (TSTEPS-2) : 1;
            #pragma unroll
            for (int m = 0; m < 3; ++m) if (vv[m])
                xr[m] = x[((size_t)(b0+vbi[m])*TSTEPS + tt)*INDIM + vxi[m]];
        }

        #pragma unroll 2
        for (int i = 0; i <= TSTEPS; ++i){
            // stage x(s+1) into xP[(i+1)&1]; then prefetch x(s+2)
            if (i <= TSTEPS-2){
                const int pxw = (i+1)&1;
                #pragma unroll
                for (int m = 0; m < 3; ++m) if (vv[m])
                    xP[pxw][vbi[m]][vxi[m]] = packhl(xr[m]);
            }
            if (i <= TSTEPS-3){
                int tt = dir ? (TSTEPS-1-(i+2)) : (i+2);
                #pragma unroll
                for (int m = 0; m < 3; ++m) if (vv[m])
                    xr[m] = x[((size_t)(b0+vbi[m])*TSTEPS + tt)*INDIM + vxi[m]];
            }
            if (i >= 1){
                const int pr = (i+1)&1;   // h1(i-1)
                const int ph = i&1;       // h2(i-2)
                short8 A2h[2], A2l[2];
                {
                    u32x4 a0 = *(const u32x4*)&h1P[pr][cl][4*g];
                    u32x4 a1 = *(const u32x4*)&h1P[pr][cl][16 + 4*g];
                    mkfrag(a0, a1, A2h[0], A2l[0]);
                    u32x4 h0 = *(const u32x4*)&h2P[ph][cl][4*g];
                    u32x4 h1_ = *(const u32x4*)&h2P[ph][cl][16 + 4*g];
                    mkfrag(h0, h1_, A2h[1], A2l[1]);
                }
                float4_ a2[3] = {{0,0,0,0},{0,0,0,0},{0,0,0,0}};
                #pragma unroll
                for (int kt = 0; kt < 2; ++kt){
                    #pragma unroll
                    for (int q = 0; q < 3; ++q) if (q < nT) a2[q] = bmfma(A2h[kt], B2h[q][kt], a2[q]);
                    #pragma unroll
                    for (int q = 0; q < 3; ++q) if (q < nT) a2[q] = bmfma(A2h[kt], B2l[q][kt], a2[q]);
                    #pragma unroll
                    for (int q = 0; q < 3; ++q) if (q < nT) a2[q] = bmfma(A2l[kt], B2h[q][kt], a2[q]);
                }
                #pragma unroll
                for (int q = 0; q < 3; ++q) if (q < nT){
                    #pragma unroll
                    for (int r = 0; r < 4; ++r)
                        z2s[4*g + r][16*(Tb+q) + cl] = a2[q][r];
                }
            }
            __syncthreads();   // barY
            if (i >= 1){
                const int pw = (i+1)&1;   // h2(i-1) buffer
                #pragma unroll
                for (int m = 0; m < 3; ++m) if (ev[m]){
                    int cc = ec[m], bb = eb[m];
                    float zi = z2s[bb][cc]      + bi2[m];
                    float zj = z2s[bb][cc+20]   + bj2[m];
                    float zf = z2s[bb][cc+40]   + bf2v[m];
                    float zo = z2s[bb][cc+60]   + bo2[m];
                    c2[m] = c2[m]*fsig(zf) + fsig(zi)*ftanh(zj);
                    float h = ftanh(c2[m])*fsig(zo);
                    h2P[pw][bb][cc] = packhl(h);
                    if ((i == 1 || i == TSTEPS) && bb < NB2){
                        int off = (i == 1) ? (dir ? 60 : 0) : (dir ? 20 : 40);
                        featws[(size_t)(b0+bb)*80 + off + cc] = h;
                    }
                }
            }
            __syncthreads();   // barX
        }
    }
}

__global__ __launch_bounds__(64) void fc_kernel(
    const float* __restrict__ featws,
    const float* __restrict__ Wfc1, const float* __restrict__ bfc1,
    const float* __restrict__ Wfc2, const float* __restrict__ bfc2,
    const float* __restrict__ Wfc3, const float* __restrict__ bfc3,
    float* __restrict__ out)
{
    __shared__ float f[80];
    __shared__ float h1b[80];
    __shared__ float h2b[20];
    const int b = blockIdx.x;
    const int lane = threadIdx.x;

    for (int i = lane; i < 80; i += 64) f[i] = featws[(size_t)b*80 + i];
    __syncthreads();
    for (int j = lane; j < 80; j += 64){
        float s = bfc1[j];
        #pragma unroll 8
        for (int k = 0; k < 80; ++k) s += f[k]*Wfc1[k*80 + j];
        h1b[j] = ftanh(s);
    }
    __syncthreads();
    if (lane < 20){
        float s = bfc2[lane];
        #pragma unroll 8
        for (int k = 0; k < 80; ++k) s += h1b[k]*Wfc2[k*20 + lane];
        h2b[lane] = ftanh(s);
    }
    __syncthreads();
    if (lane < 3){
        float s = bfc3[lane];
        #pragma unroll
        for (int k = 0; k < 20; ++k) s += h2b[k]*Wfc3[k*3 + lane];
        out[(size_t)b*3 + lane] = s;
    }
}

extern "C" void kernel_launch(void* const* d_in, const int* in_sizes, int n_in,
                              void* d_out, int out_size, void* d_ws, size_t ws_size,
                              hipStream_t stream) {
    const float* x    = (const float*)d_in[0];
    const float* Wf1  = (const float*)d_in[1];
    const float* bf1  = (const float*)d_in[2];
    const float* Wf2  = (const float*)d_in[3];
    const float* bf2  = (const float*)d_in[4];
    const float* Wb1  = (const float*)d_in[5];
    const float* bb1  = (const float*)d_in[6];
    const float* Wb2  = (const float*)d_in[7];
    const float* bb2  = (const float*)d_in[8];
    const float* Wfc1 = (const float*)d_in[9];
    const float* bfc1 = (const float*)d_in[10];
    const float* Wfc2 = (const float*)d_in[11];
    const float* bfc2 = (const float*)d_in[12];
    const float* Wfc3 = (const float*)d_in[13];
    const float* bfc3 = (const float*)d_in[14];

    float* feat = (float*)d_ws; // 2048*80*4 = 655360 B

    rnn_kernel<<<dim3(2048/NB2, 2), 256, 0, stream>>>(
        x, Wf1, bf1, Wf2, bf2, Wb1, bb1, Wb2, bb2, feat);
    fc_kernel<<<2048, 64, 0, stream>>>(
        feat, Wfc1, bfc1, Wfc2, bfc2, Wfc3, bfc3, (float*)d_out);
}